// Round 12
// baseline (50.138 us; speedup 1.0000x reference)
//
#include <hip/hip_runtime.h>

#define PPB 4  // waves per 256-thread block

typedef float v2f __attribute__((ext_vector_type(2)));

__device__ __forceinline__ float frcp(float x) { return __builtin_amdgcn_rcpf(x); }

__device__ __forceinline__ v2f vfma2(v2f a, v2f b, v2f c) {
#if __has_builtin(__builtin_elementwise_fma)
  return __builtin_elementwise_fma(a, b, c);
#else
  v2f d; d.x = fmaf(a.x, b.x, c.x); d.y = fmaf(a.y, b.y, c.y); return d;
#endif
}
__device__ __forceinline__ v2f bc(float x) { v2f p; p.x = x; p.y = x; return p; }

// packed FastGRNN gate update (2 independent recurrences per lane)
__device__ __forceinline__ v2f gate2(v2f pre, v2f h, v2f bgB, v2f KB, v2f nzgB,
                                     v2f AB, bool first) {
  v2f a = pre + bgB;
  v2f s; s.x = __expf(-a.x); s.y = __expf(-a.y);
  v2f one = bc(1.f);
  v2f zd = s + one;
  v2f z; z.x = frcp(zd.x); z.y = frcp(zd.y);
  v2f u = (s * s) * KB;
  v2f cd = u + one;
  v2f cr; cr.x = frcp(cd.x); cr.y = frcp(cd.y);
  v2f cc = vfma2(cr, bc(2.f), bc(-1.f));
  v2f m = vfma2(z, nzgB, AB);
  v2f mc = m * cc;
  return first ? mc : vfma2(z, h, mc);
}

// ---------------- Kernel 0: wx = x . W1 once per pixel, dual layout ----------------
// Lane = (p,j): 8 pixels x 8 outputs per wave-iter. W1 column j in VGPRs.
// wxr[b][y][x][8] coalesced; wxc[b][x][y][8] transposed (32B-chunk scatter).
__global__ __launch_bounds__(256) void wx_kernel(
    const float* __restrict__ inp, const float* __restrict__ W1,
    float* __restrict__ wxr, float* __restrict__ wxc) {
  const int tid = threadIdx.x, wv = tid >> 6, lane = tid & 63;
  const int p = lane >> 3, j = lane & 7;
  const int gw = blockIdx.x * 4 + wv;  // 3136 waves

  float w1c[16];
#pragma unroll
  for (int ci = 0; ci < 16; ++ci) w1c[ci] = W1[ci * 8 + j];

#pragma unroll 1
  for (int it = 0; it < 16; ++it) {
    const int pixel = (gw * 16 + it) * 8 + p;  // < 401408
    const float* src = inp + (size_t)pixel * 16;
    float4 x0 = ((const float4*)src)[0], x1 = ((const float4*)src)[1],
           x2 = ((const float4*)src)[2], x3 = ((const float4*)src)[3];
    float a = x0.x * w1c[0];
    a = fmaf(x0.y, w1c[1], a);
    a = fmaf(x0.z, w1c[2], a);
    a = fmaf(x0.w, w1c[3], a);
    a = fmaf(x1.x, w1c[4], a);
    a = fmaf(x1.y, w1c[5], a);
    a = fmaf(x1.z, w1c[6], a);
    a = fmaf(x1.w, w1c[7], a);
    a = fmaf(x2.x, w1c[8], a);
    a = fmaf(x2.y, w1c[9], a);
    a = fmaf(x2.z, w1c[10], a);
    a = fmaf(x2.w, w1c[11], a);
    a = fmaf(x3.x, w1c[12], a);
    a = fmaf(x3.y, w1c[13], a);
    a = fmaf(x3.z, w1c[14], a);
    a = fmaf(x3.w, w1c[15], a);
    wxr[(size_t)pixel * 8 + j] = a;
    const int b = pixel / 12544;
    const int rem = pixel - b * 12544;
    const int y = rem / 112, x = rem - y * 112;
    wxc[((size_t)(b * 112 + x) * 112 + y) * 8 + j] = a;
  }
}

// ---------------- Kernel A: dedup'd level-1 recurrences (wx from global) ----------------
// R6 structure minus the wx phase: 2 tiles packed per wave, h-sharing in LDS.
__global__ __launch_bounds__(256) void l1_kernel(
    const float* __restrict__ wxr, const float* __restrict__ wxc,
    const float* __restrict__ U1, const float* __restrict__ bg1,
    const float* __restrict__ bu1, const float* __restrict__ zeta1,
    const float* __restrict__ nu1, float* __restrict__ hrowg,
    float* __restrict__ hcolg) {
  constexpr int NP = 6048;  // 32 * 7 * 27 pair-waves per mode
  constexpr int SH = 18;    // hp seq stride (v2 units)

  __shared__ v2f hp[PPB][7 * SH + 8];

  const int tid = threadIdx.x, wv = tid >> 6, lane = tid & 63;
  const int widx = blockIdx.x * PPB + wv;

  const bool isrow = widx < NP;
  const int v = isrow ? widx : widx - NP;
  const int b = v / 189;     // 7*27
  const int rem = v % 189;
  const int k = rem / 27;    // tile-pair index (0..6)
  const int t27 = rem % 27;  // window index

  const int seq = lane >> 3, hid = lane & 7;

  // wx addresses: ((b*112 + q)*112 + t27*4 + t)*8 + hid, q = k*16+seq (+8 tile1)
  const float* wxbase = isrow ? wxr : wxc;
  const size_t base0 = ((size_t)(b * 112 + k * 16 + seq) * 112 + t27 * 4) * 8 + hid;
  const size_t base1 = base0 + (size_t)8 * 112 * 8;

  v2f u1b[8];
#pragma unroll
  for (int i = 0; i < 8; ++i) u1b[i] = bc(U1[i * 8 + hid]);
  const float bg1v = bg1[hid], bu1v = bu1[hid];
  const float zg1 = frcp(1.f + __expf(-zeta1[0]));
  const float ng1 = frcp(1.f + __expf(-nu1[0]));
  const v2f bgB = bc(bg1v);
  const v2f KB = bc(__expf(2.f * (bg1v - bu1v)));
  const v2f nzgB = bc(-zg1);
  const v2f AB = bc(zg1 + ng1);

  v2f* hq = &hp[wv][0];
  v2f h = bc(0.f);
  {  // t = 0
    v2f pre;
    pre.x = wxbase[base0];
    pre.y = wxbase[base1];
    h = gate2(pre, h, bgB, KB, nzgB, AB, true);
    hq[seq * SH + hid] = h;
  }
  __builtin_amdgcn_wave_barrier();
#pragma unroll
  for (int t = 1; t < 8; ++t) {
    const float4* hr4 = (const float4*)&hq[seq * SH];
    float4 f0 = hr4[0], f1 = hr4[1], f2 = hr4[2], f3 = hr4[3];
    v2f q = v2f{f0.x, f0.y} * u1b[0];
    q = vfma2(v2f{f0.z, f0.w}, u1b[1], q);
    q = vfma2(v2f{f1.x, f1.y}, u1b[2], q);
    q = vfma2(v2f{f1.z, f1.w}, u1b[3], q);
    q = vfma2(v2f{f2.x, f2.y}, u1b[4], q);
    q = vfma2(v2f{f2.z, f2.w}, u1b[5], q);
    q = vfma2(v2f{f3.x, f3.y}, u1b[6], q);
    q = vfma2(v2f{f3.z, f3.w}, u1b[7], q);
    v2f pre;
    pre.x = wxbase[base0 + t * 8];
    pre.y = wxbase[base1 + t * 8];
    pre = pre + q;
    h = gate2(pre, h, bgB, KB, nzgB, AB, false);
    hq[seq * SH + hid] = h;
    __builtin_amdgcn_wave_barrier();
  }

  // out: [b][t27][q][hid]; tile0 at k*16+seq, tile1 +8 (= +64 floats)
  const size_t obase = (((size_t)(b * 27 + t27) * 112) + k * 16 + seq) * 8 + hid;
  float* dst = isrow ? hrowg : hcolg;
  dst[obase] = h.x;
  dst[obase + 64] = h.y;
}

// ---------------- Kernel B: level-2, 2 patches (packed) per wave (R6 verbatim) ----------------
__global__ __launch_bounds__(256) void l2_kernel(
    const float* __restrict__ hrowg, const float* __restrict__ hcolg,
    const float* __restrict__ W2, const float* __restrict__ U2,
    const float* __restrict__ bg2, const float* __restrict__ bu2,
    const float* __restrict__ zeta2, const float* __restrict__ nu2,
    float* __restrict__ out) {
  constexpr int GST = 18;  // h2 branch stride (v2 units)
  constexpr int WHT = 18;  // wh row stride (v2 units)
  __shared__ v2f hbI[PPB][128];
  __shared__ v2f whb[PPB][2 * 8 * WHT];
  __shared__ v2f h2I[PPB][3 * GST + 16];

  const int tid = threadIdx.x, wv = tid >> 6, lane = tid & 63;
  const int w = blockIdx.x * PPB + wv;
  const int n0 = 2 * w, n1 = n0 + 1;

  {
    const int p = lane >> 5, half = (lane >> 4) & 1, idx = lane & 15;
    const int pn = p ? n1 : n0;
    const int pw = pn % 27;
    const int qq = pn / 27;
    const int ph = qq % 27, bb = qq / 27;
    const float* src = half ? &hcolg[(((size_t)(bb * 27 + ph)) * 112 + pw * 4) * 8]
                            : &hrowg[(((size_t)(bb * 27 + pw)) * 112 + ph * 4) * 8];
    float4 val = ((const float4*)src)[idx];
    float* base = (float*)&hbI[wv][half * 64 + idx * 4];
    base[0 + p] = val.x;
    base[2 + p] = val.y;
    base[4 + p] = val.z;
    base[6 + p] = val.w;
  }
  __builtin_amdgcn_wave_barrier();

  const int g = lane >> 4, j = lane & 15;
  v2f w2b[8], u2b[16];
#pragma unroll
  for (int d = 0; d < 8; ++d) w2b[d] = bc(W2[d * 16 + j]);
#pragma unroll
  for (int i = 0; i < 16; ++i) u2b[i] = bc(U2[i * 16 + j]);
  const float bg2v = bg2[j], bu2v = bu2[j];
  const float zg2 = frcp(1.f + __expf(-zeta2[0]));
  const float ng2 = frcp(1.f + __expf(-nu2[0]));
  const v2f bgB = bc(bg2v);
  const v2f KB = bc(__expf(2.f * (bg2v - bu2v)));
  const v2f nzgB = bc(-zg2);
  const v2f AB = bc(zg2 + ng2);

  const int src = g >> 1;

  {
    const v2f* hb = &hbI[wv][src * 64];
    const int t0 = (g & 1) * 4;
#pragma unroll
    for (int i = 0; i < 4; ++i) {
      const int t = t0 + i;
      const v2f* hr = &hb[t * 8];
      v2f p = hr[0] * w2b[0];
#pragma unroll
      for (int d = 1; d < 8; ++d) p = vfma2(hr[d], w2b[d], p);
      whb[wv][(src * 8 + t) * WHT + j] = p;
    }
  }
  __builtin_amdgcn_wave_barrier();

  const v2f* whsrc = &whb[wv][src * 8 * WHT];
  v2f* h2q = &h2I[wv][g * GST];

  v2f h2 = bc(0.f);
  {
    const int tt = (g & 1) ? 7 : 0;
    v2f p = whsrc[tt * WHT + j];
    h2 = gate2(p, h2, bgB, KB, nzgB, AB, true);
    h2q[j] = h2;
  }
  __builtin_amdgcn_wave_barrier();
#pragma unroll
  for (int t = 1; t < 8; ++t) {
    const int tt = (g & 1) ? (7 - t) : t;
    v2f p = whsrc[tt * WHT + j];
    const float4* q4 = (const float4*)h2q;
    float4 v0 = q4[0], v1 = q4[1], v2_ = q4[2], v3 = q4[3];
    float4 v4 = q4[4], v5 = q4[5], v6 = q4[6], v7 = q4[7];
    v2f q = v2f{v0.x, v0.y} * u2b[0];
    q = vfma2(v2f{v0.z, v0.w}, u2b[1], q);
    q = vfma2(v2f{v1.x, v1.y}, u2b[2], q);
    q = vfma2(v2f{v1.z, v1.w}, u2b[3], q);
    q = vfma2(v2f{v2_.x, v2_.y}, u2b[4], q);
    q = vfma2(v2f{v2_.z, v2_.w}, u2b[5], q);
    q = vfma2(v2f{v3.x, v3.y}, u2b[6], q);
    q = vfma2(v2f{v3.z, v3.w}, u2b[7], q);
    q = vfma2(v2f{v4.x, v4.y}, u2b[8], q);
    q = vfma2(v2f{v4.z, v4.w}, u2b[9], q);
    q = vfma2(v2f{v5.x, v5.y}, u2b[10], q);
    q = vfma2(v2f{v5.z, v5.w}, u2b[11], q);
    q = vfma2(v2f{v6.x, v6.y}, u2b[12], q);
    q = vfma2(v2f{v6.z, v6.w}, u2b[13], q);
    q = vfma2(v2f{v7.x, v7.y}, u2b[14], q);
    q = vfma2(v2f{v7.z, v7.w}, u2b[15], q);
    v2f pre = p + q;
    h2 = gate2(pre, h2, bgB, KB, nzgB, AB, false);
    if (t < 7) {
      h2q[j] = h2;
      __builtin_amdgcn_wave_barrier();
    }
  }

  out[(size_t)n0 * 64 + lane] = h2.x;
  out[(size_t)n1 * 64 + lane] = h2.y;
}

extern "C" void kernel_launch(void* const* d_in, const int* in_sizes, int n_in,
                              void* d_out, int out_size, void* d_ws, size_t ws_size,
                              hipStream_t stream) {
  const float* inp   = (const float*)d_in[0];
  const float* W1    = (const float*)d_in[1];
  const float* U1    = (const float*)d_in[2];
  const float* bg1   = (const float*)d_in[3];
  const float* bu1   = (const float*)d_in[4];
  const float* zeta1 = (const float*)d_in[5];
  const float* nu1   = (const float*)d_in[6];
  const float* W2    = (const float*)d_in[7];
  const float* U2    = (const float*)d_in[8];
  const float* bg2   = (const float*)d_in[9];
  const float* bu2   = (const float*)d_in[10];
  const float* zeta2 = (const float*)d_in[11];
  const float* nu2   = (const float*)d_in[12];
  float* out = (float*)d_out;

  const size_t WXSZ = (size_t)32 * 112 * 112 * 8;  // 3211264 floats
  const size_t HSZ = (size_t)32 * 27 * 112 * 8;    // 774144 floats
  float* wxr = (float*)d_ws;
  float* wxc = wxr + WXSZ;
  float* hrowg = wxc + WXSZ;
  float* hcolg = hrowg + HSZ;

  // K0: 401408 pixels, 8/wave-iter, 16 iters/wave, 4 waves/block -> 784 blocks
  wx_kernel<<<dim3(784), dim3(256), 0, stream>>>(inp, W1, wxr, wxc);
  // K1: 12096 pair-waves (row+col), 4/block
  l1_kernel<<<dim3(3024), dim3(256), 0, stream>>>(
      wxr, wxc, U1, bg1, bu1, zeta1, nu1, hrowg, hcolg);
  // K2: 11664 patch-pair waves, 4/block
  l2_kernel<<<dim3(2916), dim3(256), 0, stream>>>(
      hrowg, hcolg, W2, U2, bg2, bu2, zeta2, nu2, out);
}

// Round 13
// 44.155 us; speedup vs baseline: 1.1355x; 1.1355x over previous
//
#include <hip/hip_runtime.h>

#define PPB 4  // waves per 256-thread block

typedef float v2f __attribute__((ext_vector_type(2)));

__device__ __forceinline__ float frcp(float x) { return __builtin_amdgcn_rcpf(x); }

__device__ __forceinline__ v2f vfma2(v2f a, v2f b, v2f c) {
#if __has_builtin(__builtin_elementwise_fma)
  return __builtin_elementwise_fma(a, b, c);
#else
  v2f d; d.x = fmaf(a.x, b.x, c.x); d.y = fmaf(a.y, b.y, c.y); return d;
#endif
}
__device__ __forceinline__ v2f bc(float x) { v2f p; p.x = x; p.y = x; return p; }

// packed FastGRNN gate update (2 independent recurrences per lane)
__device__ __forceinline__ v2f gate2(v2f pre, v2f h, v2f bgB, v2f KB, v2f nzgB,
                                     v2f AB, bool first) {
  v2f a = pre + bgB;
  v2f s; s.x = __expf(-a.x); s.y = __expf(-a.y);
  v2f one = bc(1.f);
  v2f zd = s + one;
  v2f z; z.x = frcp(zd.x); z.y = frcp(zd.y);
  v2f u = (s * s) * KB;
  v2f cd = u + one;
  v2f cr; cr.x = frcp(cd.x); cr.y = frcp(cd.y);
  v2f cc = vfma2(cr, bc(2.f), bc(-1.f));
  v2f m = vfma2(z, nzgB, AB);
  v2f mc = m * cc;
  return first ? mc : vfma2(z, h, mc);
}

// ---------------- Kernel 0: wx = x . W1 once per pixel (single layout) ----------------
// Lane = (p,j): 8 pixels x 8 outputs per wave-iter; W1 column j in VGPRs.
__global__ __launch_bounds__(256) void wx_kernel(
    const float* __restrict__ inp, const float* __restrict__ W1,
    float* __restrict__ wxr) {
  const int tid = threadIdx.x, wv = tid >> 6, lane = tid & 63;
  const int p = lane >> 3, j = lane & 7;
  const int gw = blockIdx.x * 4 + wv;  // 3136 waves

  float w1c[16];
#pragma unroll
  for (int ci = 0; ci < 16; ++ci) w1c[ci] = W1[ci * 8 + j];

#pragma unroll 1
  for (int it = 0; it < 16; ++it) {
    const int pixel = (gw * 16 + it) * 8 + p;  // < 401408
    const float* src = inp + (size_t)pixel * 16;
    float4 x0 = ((const float4*)src)[0], x1 = ((const float4*)src)[1],
           x2 = ((const float4*)src)[2], x3 = ((const float4*)src)[3];
    float a = x0.x * w1c[0];
    a = fmaf(x0.y, w1c[1], a);
    a = fmaf(x0.z, w1c[2], a);
    a = fmaf(x0.w, w1c[3], a);
    a = fmaf(x1.x, w1c[4], a);
    a = fmaf(x1.y, w1c[5], a);
    a = fmaf(x1.z, w1c[6], a);
    a = fmaf(x1.w, w1c[7], a);
    a = fmaf(x2.x, w1c[8], a);
    a = fmaf(x2.y, w1c[9], a);
    a = fmaf(x2.z, w1c[10], a);
    a = fmaf(x2.w, w1c[11], a);
    a = fmaf(x3.x, w1c[12], a);
    a = fmaf(x3.y, w1c[13], a);
    a = fmaf(x3.z, w1c[14], a);
    a = fmaf(x3.w, w1c[15], a);
    wxr[(size_t)pixel * 8 + j] = a;
  }
}

// ---------------- Kernel A: level-1 recurrences, wx bulk-staged to LDS ----------------
// R6 recurrence verbatim; wx phase replaced by a coalesced 1024-float stage.
__global__ __launch_bounds__(256) void l1_kernel(
    const float* __restrict__ wxr, const float* __restrict__ U1,
    const float* __restrict__ bg1, const float* __restrict__ bu1,
    const float* __restrict__ zeta1, const float* __restrict__ nu1,
    float* __restrict__ hrowg, float* __restrict__ hcolg) {
  constexpr int NP = 6048;  // 32 * 7 * 27 pair-waves per mode
  constexpr int SH = 18;    // hp seq stride (v2 units)
  constexpr int RST = 72;   // row-mode LDS stride (16 rows x 64 + 8 pad)
  constexpr int CST = 136;  // col-mode LDS stride (8 rows x 128 + 8 pad)

  __shared__ float wxs[PPB][16 * RST];  // 1152 floats/wave (>= 8*136 = 1088)
  __shared__ v2f hp[PPB][7 * SH + 8];

  const int tid = threadIdx.x, wv = tid >> 6, lane = tid & 63;
  const int widx = blockIdx.x * PPB + wv;

  const bool isrow = widx < NP;
  const int v = isrow ? widx : widx - NP;
  const int b = v / 189;     // 7*27
  const int rem = v % 189;
  const int k = rem / 27;    // tile-pair index (0..6)
  const int t27 = rem % 27;  // window index

  // ---- stage wx block: row: 16 chunks x 64 floats; col: 8 chunks x 128 ----
  {
    const size_t src_base = isrow
        ? (((size_t)(b * 112 + k * 16) * 112) + t27 * 4) * 8
        : (((size_t)(b * 112 + t27 * 4) * 112) + k * 16) * 8;
    const int chunk = isrow ? (lane >> 2) : (lane >> 3);
    const int i0 = isrow ? ((lane & 3) << 4) : ((lane & 7) << 4);
    const int st = isrow ? RST : CST;
    const float* src = wxr + src_base + chunk * 896 + i0;
    float* dst = &wxs[wv][chunk * st + i0];
    float4 c0 = ((const float4*)src)[0];
    float4 c1 = ((const float4*)src)[1];
    float4 c2 = ((const float4*)src)[2];
    float4 c3 = ((const float4*)src)[3];
    ((float4*)dst)[0] = c0;
    ((float4*)dst)[1] = c1;
    ((float4*)dst)[2] = c2;
    ((float4*)dst)[3] = c3;
  }
  __builtin_amdgcn_wave_barrier();

  const int seq = lane >> 3, hid = lane & 7;

  // wx LDS addresses per step t: row: seq*RST + t*8 + hid (tile1: +8 rows);
  // col: t*CST + seq*8 + hid (tile1: +64)
  const int a0 = isrow ? (seq * RST + hid) : (seq * 8 + hid);
  const int a1 = isrow ? ((seq + 8) * RST + hid) : (seq * 8 + 64 + hid);
  const int astep = isrow ? 8 : CST;

  v2f u1b[8];
#pragma unroll
  for (int i = 0; i < 8; ++i) u1b[i] = bc(U1[i * 8 + hid]);
  const float bg1v = bg1[hid], bu1v = bu1[hid];
  const float zg1 = frcp(1.f + __expf(-zeta1[0]));
  const float ng1 = frcp(1.f + __expf(-nu1[0]));
  const v2f bgB = bc(bg1v);
  const v2f KB = bc(__expf(2.f * (bg1v - bu1v)));
  const v2f nzgB = bc(-zg1);
  const v2f AB = bc(zg1 + ng1);

  v2f* hq = &hp[wv][0];
  v2f h = bc(0.f);
  {  // t = 0
    v2f pre;
    pre.x = wxs[wv][a0];
    pre.y = wxs[wv][a1];
    h = gate2(pre, h, bgB, KB, nzgB, AB, true);
    hq[seq * SH + hid] = h;
  }
  __builtin_amdgcn_wave_barrier();
#pragma unroll
  for (int t = 1; t < 8; ++t) {
    const float4* hr4 = (const float4*)&hq[seq * SH];
    float4 f0 = hr4[0], f1 = hr4[1], f2 = hr4[2], f3 = hr4[3];
    v2f q = v2f{f0.x, f0.y} * u1b[0];
    q = vfma2(v2f{f0.z, f0.w}, u1b[1], q);
    q = vfma2(v2f{f1.x, f1.y}, u1b[2], q);
    q = vfma2(v2f{f1.z, f1.w}, u1b[3], q);
    q = vfma2(v2f{f2.x, f2.y}, u1b[4], q);
    q = vfma2(v2f{f2.z, f2.w}, u1b[5], q);
    q = vfma2(v2f{f3.x, f3.y}, u1b[6], q);
    q = vfma2(v2f{f3.z, f3.w}, u1b[7], q);
    v2f pre;
    pre.x = wxs[wv][a0 + t * astep];
    pre.y = wxs[wv][a1 + t * astep];
    pre = pre + q;
    h = gate2(pre, h, bgB, KB, nzgB, AB, false);
    hq[seq * SH + hid] = h;
    __builtin_amdgcn_wave_barrier();
  }

  // out: [b][t27][q][hid]; tile0 at k*16+seq, tile1 +8 (= +64 floats)
  const size_t obase = (((size_t)(b * 27 + t27) * 112) + k * 16 + seq) * 8 + hid;
  float* dst = isrow ? hrowg : hcolg;
  dst[obase] = h.x;
  dst[obase + 64] = h.y;
}

// ---------------- Kernel B: level-2, 2 patches (packed) per wave (R6 verbatim) ----------------
__global__ __launch_bounds__(256) void l2_kernel(
    const float* __restrict__ hrowg, const float* __restrict__ hcolg,
    const float* __restrict__ W2, const float* __restrict__ U2,
    const float* __restrict__ bg2, const float* __restrict__ bu2,
    const float* __restrict__ zeta2, const float* __restrict__ nu2,
    float* __restrict__ out) {
  constexpr int GST = 18;  // h2 branch stride (v2 units)
  constexpr int WHT = 18;  // wh row stride (v2 units)
  __shared__ v2f hbI[PPB][128];
  __shared__ v2f whb[PPB][2 * 8 * WHT];
  __shared__ v2f h2I[PPB][3 * GST + 16];

  const int tid = threadIdx.x, wv = tid >> 6, lane = tid & 63;
  const int w = blockIdx.x * PPB + wv;
  const int n0 = 2 * w, n1 = n0 + 1;

  {
    const int p = lane >> 5, half = (lane >> 4) & 1, idx = lane & 15;
    const int pn = p ? n1 : n0;
    const int pw = pn % 27;
    const int qq = pn / 27;
    const int ph = qq % 27, bb = qq / 27;
    const float* src = half ? &hcolg[(((size_t)(bb * 27 + ph)) * 112 + pw * 4) * 8]
                            : &hrowg[(((size_t)(bb * 27 + pw)) * 112 + ph * 4) * 8];
    float4 val = ((const float4*)src)[idx];
    float* base = (float*)&hbI[wv][half * 64 + idx * 4];
    base[0 + p] = val.x;
    base[2 + p] = val.y;
    base[4 + p] = val.z;
    base[6 + p] = val.w;
  }
  __builtin_amdgcn_wave_barrier();

  const int g = lane >> 4, j = lane & 15;
  v2f w2b[8], u2b[16];
#pragma unroll
  for (int d = 0; d < 8; ++d) w2b[d] = bc(W2[d * 16 + j]);
#pragma unroll
  for (int i = 0; i < 16; ++i) u2b[i] = bc(U2[i * 16 + j]);
  const float bg2v = bg2[j], bu2v = bu2[j];
  const float zg2 = frcp(1.f + __expf(-zeta2[0]));
  const float ng2 = frcp(1.f + __expf(-nu2[0]));
  const v2f bgB = bc(bg2v);
  const v2f KB = bc(__expf(2.f * (bg2v - bu2v)));
  const v2f nzgB = bc(-zg2);
  const v2f AB = bc(zg2 + ng2);

  const int src = g >> 1;

  {
    const v2f* hb = &hbI[wv][src * 64];
    const int t0 = (g & 1) * 4;
#pragma unroll
    for (int i = 0; i < 4; ++i) {
      const int t = t0 + i;
      const v2f* hr = &hb[t * 8];
      v2f p = hr[0] * w2b[0];
#pragma unroll
      for (int d = 1; d < 8; ++d) p = vfma2(hr[d], w2b[d], p);
      whb[wv][(src * 8 + t) * WHT + j] = p;
    }
  }
  __builtin_amdgcn_wave_barrier();

  const v2f* whsrc = &whb[wv][src * 8 * WHT];
  v2f* h2q = &h2I[wv][g * GST];

  v2f h2 = bc(0.f);
  {
    const int tt = (g & 1) ? 7 : 0;
    v2f p = whsrc[tt * WHT + j];
    h2 = gate2(p, h2, bgB, KB, nzgB, AB, true);
    h2q[j] = h2;
  }
  __builtin_amdgcn_wave_barrier();
#pragma unroll
  for (int t = 1; t < 8; ++t) {
    const int tt = (g & 1) ? (7 - t) : t;
    v2f p = whsrc[tt * WHT + j];
    const float4* q4 = (const float4*)h2q;
    float4 v0 = q4[0], v1 = q4[1], v2_ = q4[2], v3 = q4[3];
    float4 v4 = q4[4], v5 = q4[5], v6 = q4[6], v7 = q4[7];
    v2f q = v2f{v0.x, v0.y} * u2b[0];
    q = vfma2(v2f{v0.z, v0.w}, u2b[1], q);
    q = vfma2(v2f{v1.x, v1.y}, u2b[2], q);
    q = vfma2(v2f{v1.z, v1.w}, u2b[3], q);
    q = vfma2(v2f{v2_.x, v2_.y}, u2b[4], q);
    q = vfma2(v2f{v2_.z, v2_.w}, u2b[5], q);
    q = vfma2(v2f{v3.x, v3.y}, u2b[6], q);
    q = vfma2(v2f{v3.z, v3.w}, u2b[7], q);
    q = vfma2(v2f{v4.x, v4.y}, u2b[8], q);
    q = vfma2(v2f{v4.z, v4.w}, u2b[9], q);
    q = vfma2(v2f{v5.x, v5.y}, u2b[10], q);
    q = vfma2(v2f{v5.z, v5.w}, u2b[11], q);
    q = vfma2(v2f{v6.x, v6.y}, u2b[12], q);
    q = vfma2(v2f{v6.z, v6.w}, u2b[13], q);
    q = vfma2(v2f{v7.x, v7.y}, u2b[14], q);
    q = vfma2(v2f{v7.z, v7.w}, u2b[15], q);
    v2f pre = p + q;
    h2 = gate2(pre, h2, bgB, KB, nzgB, AB, false);
    if (t < 7) {
      h2q[j] = h2;
      __builtin_amdgcn_wave_barrier();
    }
  }

  out[(size_t)n0 * 64 + lane] = h2.x;
  out[(size_t)n1 * 64 + lane] = h2.y;
}

extern "C" void kernel_launch(void* const* d_in, const int* in_sizes, int n_in,
                              void* d_out, int out_size, void* d_ws, size_t ws_size,
                              hipStream_t stream) {
  const float* inp   = (const float*)d_in[0];
  const float* W1    = (const float*)d_in[1];
  const float* U1    = (const float*)d_in[2];
  const float* bg1   = (const float*)d_in[3];
  const float* bu1   = (const float*)d_in[4];
  const float* zeta1 = (const float*)d_in[5];
  const float* nu1   = (const float*)d_in[6];
  const float* W2    = (const float*)d_in[7];
  const float* U2    = (const float*)d_in[8];
  const float* bg2   = (const float*)d_in[9];
  const float* bu2   = (const float*)d_in[10];
  const float* zeta2 = (const float*)d_in[11];
  const float* nu2   = (const float*)d_in[12];
  float* out = (float*)d_out;

  const size_t WXSZ = (size_t)32 * 112 * 112 * 8;  // 3211264 floats
  const size_t HSZ = (size_t)32 * 27 * 112 * 8;    // 774144 floats
  float* wxr = (float*)d_ws;
  float* hrowg = wxr + WXSZ;
  float* hcolg = hrowg + HSZ;

  // K0: 401408 pixels, 8/wave-iter, 16 iters/wave, 4 waves/block
  wx_kernel<<<dim3(784), dim3(256), 0, stream>>>(inp, W1, wxr);
  // K1: 12096 pair-waves (row+col), 4/block
  l1_kernel<<<dim3(3024), dim3(256), 0, stream>>>(
      wxr, U1, bg1, bu1, zeta1, nu1, hrowg, hcolg);
  // K2: 11664 patch-pair waves, 4/block
  l2_kernel<<<dim3(2916), dim3(256), 0, stream>>>(
      hrowg, hcolg, W2, U2, bg2, bu2, zeta2, nu2, out);
}

// Round 14
// 38.432 us; speedup vs baseline: 1.3046x; 1.1489x over previous
//
#include <hip/hip_runtime.h>

#define PPB 4  // waves per 256-thread block

typedef float v2f __attribute__((ext_vector_type(2)));

__device__ __forceinline__ float frcp(float x) { return __builtin_amdgcn_rcpf(x); }

__device__ __forceinline__ v2f vfma2(v2f a, v2f b, v2f c) {
#if __has_builtin(__builtin_elementwise_fma)
  return __builtin_elementwise_fma(a, b, c);
#else
  v2f d; d.x = fmaf(a.x, b.x, c.x); d.y = fmaf(a.y, b.y, c.y); return d;
#endif
}
__device__ __forceinline__ v2f bc(float x) { v2f p; p.x = x; p.y = x; return p; }

// DPP helpers (mov_dpp validated on this HW in R9/R10)
template <int CTRL>
__device__ __forceinline__ float dppf(float x) {
  return __int_as_float(
      __builtin_amdgcn_mov_dpp(__float_as_int(x), CTRL, 0xf, 0xf, true));
}
template <int P>  // broadcast sub-lane P within each quad (quad_perm [P,P,P,P])
__device__ __forceinline__ v2f qbcast(v2f v) {
  constexpr int ctrl = P * 0x55;
  v2f r; r.x = dppf<ctrl>(v.x); r.y = dppf<ctrl>(v.y); return r;
}
template <int K>  // row_ror:K within 16-lane rows
__device__ __forceinline__ v2f rot16(v2f v) {
  constexpr int ctrl = 0x120 + K;
  v2f r; r.x = dppf<ctrl>(v.x); r.y = dppf<ctrl>(v.y); return r;
}

// packed FastGRNN gate update (2 states per lane)
__device__ __forceinline__ v2f gate2(v2f pre, v2f h, v2f bgB, v2f KB, v2f nzgB,
                                     v2f AB, bool first) {
  v2f a = pre + bgB;
  v2f s; s.x = __expf(-a.x); s.y = __expf(-a.y);
  v2f one = bc(1.f);
  v2f zd = s + one;
  v2f z; z.x = frcp(zd.x); z.y = frcp(zd.y);
  v2f u = (s * s) * KB;
  v2f cd = u + one;
  v2f cr; cr.x = frcp(cd.x); cr.y = frcp(cd.y);
  v2f cc = vfma2(cr, bc(2.f), bc(-1.f));
  v2f m = vfma2(z, nzgB, AB);
  v2f mc = m * cc;
  return first ? mc : vfma2(z, h, mc);
}

// ---------------- Kernel A: level-1; wx phase = R6; recurrence = quad-DPP ----------------
__global__ __launch_bounds__(256) void l1_kernel(
    const float* __restrict__ inp, const float* __restrict__ W1,
    const float* __restrict__ U1, const float* __restrict__ bg1,
    const float* __restrict__ bu1, const float* __restrict__ zeta1,
    const float* __restrict__ nu1, float* __restrict__ hrowg,
    float* __restrict__ hcolg) {
  constexpr int NP = 6048;    // 32 * 7 * 27 pair-waves per mode
  constexpr int TS = 132;     // wx t-stride (floats): [8 t][16 q][8 hid] + pad
  constexpr int TILE1 = 8 * TS;  // 1056

  __shared__ float w1s[128];
  __shared__ float wxs[PPB][2 * TILE1 + 16];

  const int tid = threadIdx.x, wv = tid >> 6, lane = tid & 63;
  const int widx = blockIdx.x * PPB + wv;

  if (tid < 32) ((float4*)w1s)[tid] = ((const float4*)W1)[tid];
  __syncthreads();

  const bool isrow = widx < NP;
  const int v = isrow ? widx : widx - NP;
  const int b = v / 189;     // 7*27
  const int rem = v % 189;
  const int k = rem / 27;    // tile-pair index (0..6)
  const int t27 = rem % 27;  // window index

  const int rr = lane >> 3, cc = lane & 7;
  const int ay = isrow ? (k * 16 + rr) : (t27 * 4 + rr);
  const int ax = isrow ? (t27 * 4 + cc) : (k * 16 + cc);
  const int by = isrow ? (ay + 8) : ay;
  const int bx = isrow ? ax : (ax + 8);

  // ---- wx for both pixels (R6 verbatim), stored to [t][q][8] per tile ----
  {
    const float* pA = inp + ((size_t)(b * 112 + ay) * 112 + ax) * 16;
    const float* pB = inp + ((size_t)(b * 112 + by) * 112 + bx) * 16;
    float4 A0 = ((const float4*)pA)[0], A1 = ((const float4*)pA)[1],
           A2 = ((const float4*)pA)[2], A3 = ((const float4*)pA)[3];
    float4 B0 = ((const float4*)pB)[0], B1 = ((const float4*)pB)[1],
           B2 = ((const float4*)pB)[2], B3 = ((const float4*)pB)[3];
    float xA[16] = {A0.x, A0.y, A0.z, A0.w, A1.x, A1.y, A1.z, A1.w,
                    A2.x, A2.y, A2.z, A2.w, A3.x, A3.y, A3.z, A3.w};
    float xB[16] = {B0.x, B0.y, B0.z, B0.w, B1.x, B1.y, B1.z, B1.w,
                    B2.x, B2.y, B2.z, B2.w, B3.x, B3.y, B3.z, B3.w};
    v2f aA0 = bc(0.f), aA1 = bc(0.f), aA2 = bc(0.f), aA3 = bc(0.f);
    v2f aB0 = bc(0.f), aB1 = bc(0.f), aB2 = bc(0.f), aB3 = bc(0.f);
#pragma unroll
    for (int ci = 0; ci < 16; ++ci) {
      const v2f* wr = (const v2f*)&w1s[ci * 8];
      v2f w0 = wr[0], w1 = wr[1], w2 = wr[2], w3 = wr[3];
      v2f xa = bc(xA[ci]), xb = bc(xB[ci]);
      aA0 = vfma2(xa, w0, aA0); aA1 = vfma2(xa, w1, aA1);
      aA2 = vfma2(xa, w2, aA2); aA3 = vfma2(xa, w3, aA3);
      aB0 = vfma2(xb, w0, aB0); aB1 = vfma2(xb, w1, aB1);
      aB2 = vfma2(xb, w2, aB2); aB3 = vfma2(xb, w3, aB3);
    }
    // row-mode: t=cc, q=rr; col-mode: t=rr, q=cc
    const int tA = isrow ? cc : rr;
    const int qA = isrow ? rr : cc;
    float* wdA = &wxs[wv][tA * TS + qA * 8];
    float* wdB = wdA + TILE1;
    ((float4*)wdA)[0] = float4{aA0.x, aA0.y, aA1.x, aA1.y};
    ((float4*)wdA)[1] = float4{aA2.x, aA2.y, aA3.x, aA3.y};
    ((float4*)wdB)[0] = float4{aB0.x, aB0.y, aB1.x, aB1.y};
    ((float4*)wdB)[1] = float4{aB2.x, aB2.y, aB3.x, aB3.y};
  }
  __builtin_amdgcn_wave_barrier();

  // ---- recurrence: quad = one recurrence; sub = hid-pair; DPP exchange ----
  const int q4 = lane >> 2, sub = lane & 3;  // rec q4: tile=q4>>3, seq=q4&7
  // prefetch all 8 wx steps into registers (only LDS use of the loop)
  v2f wxv[8];
  {
    const float* base = &wxs[wv][(q4 >> 3) * TILE1 + (q4 & 7) * 8 + 2 * sub];
#pragma unroll
    for (int t = 0; t < 8; ++t) wxv[t] = *(const v2f*)(base + t * TS);
  }

  v2f u1q[8];
#pragma unroll
  for (int i = 0; i < 8; ++i) u1q[i] = *(const v2f*)&U1[i * 8 + 2 * sub];
  const v2f bgB = *(const v2f*)&bg1[2 * sub];
  const v2f buB = *(const v2f*)&bu1[2 * sub];
  const float zg1 = frcp(1.f + __expf(-zeta1[0]));
  const float ng1 = frcp(1.f + __expf(-nu1[0]));
  v2f KB; KB.x = __expf(2.f * (bgB.x - buB.x)); KB.y = __expf(2.f * (bgB.y - buB.y));
  const v2f nzgB = bc(-zg1);
  const v2f AB = bc(zg1 + ng1);

  v2f h = gate2(wxv[0], bc(0.f), bgB, KB, nzgB, AB, true);
#pragma unroll
  for (int t = 1; t < 8; ++t) {
    v2f h0 = qbcast<0>(h), h1 = qbcast<1>(h), h2_ = qbcast<2>(h), h3 = qbcast<3>(h);
    v2f q = bc(h0.x) * u1q[0];
    q = vfma2(bc(h0.y), u1q[1], q);
    q = vfma2(bc(h1.x), u1q[2], q);
    q = vfma2(bc(h1.y), u1q[3], q);
    q = vfma2(bc(h2_.x), u1q[4], q);
    q = vfma2(bc(h2_.y), u1q[5], q);
    q = vfma2(bc(h3.x), u1q[6], q);
    q = vfma2(bc(h3.y), u1q[7], q);
    h = gate2(wxv[t] + q, h, bgB, KB, nzgB, AB, false);
  }

  // out: [b][t27][k*16 + q4][hid]; this lane writes hid {2sub, 2sub+1}
  float* dst = (isrow ? hrowg : hcolg) +
               (((size_t)(b * 27 + t27) * 112) + k * 16 + q4) * 8 + 2 * sub;
  dst[0] = h.x;
  dst[1] = h.y;
}

// ---------------- Kernel B: level-2; B6 staging/whb; loop = row_ror DPP ----------------
__global__ __launch_bounds__(256) void l2_kernel(
    const float* __restrict__ hrowg, const float* __restrict__ hcolg,
    const float* __restrict__ W2, const float* __restrict__ U2,
    const float* __restrict__ bg2, const float* __restrict__ bu2,
    const float* __restrict__ zeta2, const float* __restrict__ nu2,
    float* __restrict__ out) {
  constexpr int WHT = 18;  // wh row stride (v2 units)
  __shared__ v2f hbI[PPB][128];
  __shared__ v2f whb[PPB][2 * 8 * WHT];

  const int tid = threadIdx.x, wv = tid >> 6, lane = tid & 63;
  const int w = blockIdx.x * PPB + wv;
  const int n0 = 2 * w, n1 = n0 + 1;

  {
    const int p = lane >> 5, half = (lane >> 4) & 1, idx = lane & 15;
    const int pn = p ? n1 : n0;
    const int pw = pn % 27;
    const int qq = pn / 27;
    const int ph = qq % 27, bb = qq / 27;
    const float* src = half ? &hcolg[(((size_t)(bb * 27 + ph)) * 112 + pw * 4) * 8]
                            : &hrowg[(((size_t)(bb * 27 + pw)) * 112 + ph * 4) * 8];
    float4 val = ((const float4*)src)[idx];
    float* base = (float*)&hbI[wv][half * 64 + idx * 4];
    base[0 + p] = val.x;
    base[2 + p] = val.y;
    base[4 + p] = val.z;
    base[6 + p] = val.w;
  }
  __builtin_amdgcn_wave_barrier();

  const int g = lane >> 4, j = lane & 15;
  v2f w2b[8];
#pragma unroll
  for (int d = 0; d < 8; ++d) w2b[d] = bc(W2[d * 16 + j]);
  // rotated U2 columns for row_ror mac: partner at rotr<k> is lane (j-k)&15
  v2f u2r[16];
#pragma unroll
  for (int kk = 0; kk < 16; ++kk) u2r[kk] = bc(U2[((j - kk) & 15) * 16 + j]);
  const float bg2v = bg2[j], bu2v = bu2[j];
  const float zg2 = frcp(1.f + __expf(-zeta2[0]));
  const float ng2 = frcp(1.f + __expf(-nu2[0]));
  const v2f bgB = bc(bg2v);
  const v2f KB = bc(__expf(2.f * (bg2v - bu2v)));
  const v2f nzgB = bc(-zg2);
  const v2f AB = bc(zg2 + ng2);

  const int src = g >> 1;

  // wh[src][t][j] = sum_d h[src][t][d] * W2[d][j]  (t-split by g&1; B6 verbatim)
  {
    const v2f* hb = &hbI[wv][src * 64];
    const int t0 = (g & 1) * 4;
#pragma unroll
    for (int i = 0; i < 4; ++i) {
      const int t = t0 + i;
      const v2f* hr = &hb[t * 8];
      v2f p = hr[0] * w2b[0];
#pragma unroll
      for (int d = 1; d < 8; ++d) p = vfma2(hr[d], w2b[d], p);
      whb[wv][(src * 8 + t) * WHT + j] = p;
    }
  }
  __builtin_amdgcn_wave_barrier();

  // prefetch this branch's 8 wh terms (time-ordered for fwd/rev) into registers
  v2f whv[8];
  {
    const v2f* whsrc = &whb[wv][src * 8 * WHT];
#pragma unroll
    for (int t = 0; t < 8; ++t) {
      const int tt = (g & 1) ? (7 - t) : t;
      whv[t] = whsrc[tt * WHT + j];
    }
  }

  v2f h2 = gate2(whv[0], bc(0.f), bgB, KB, nzgB, AB, true);
#pragma unroll
  for (int t = 1; t < 8; ++t) {
    v2f q = h2 * u2r[0];
    q = vfma2(rot16<1>(h2), u2r[1], q);
    q = vfma2(rot16<2>(h2), u2r[2], q);
    q = vfma2(rot16<3>(h2), u2r[3], q);
    q = vfma2(rot16<4>(h2), u2r[4], q);
    q = vfma2(rot16<5>(h2), u2r[5], q);
    q = vfma2(rot16<6>(h2), u2r[6], q);
    q = vfma2(rot16<7>(h2), u2r[7], q);
    q = vfma2(rot16<8>(h2), u2r[8], q);
    q = vfma2(rot16<9>(h2), u2r[9], q);
    q = vfma2(rot16<10>(h2), u2r[10], q);
    q = vfma2(rot16<11>(h2), u2r[11], q);
    q = vfma2(rot16<12>(h2), u2r[12], q);
    q = vfma2(rot16<13>(h2), u2r[13], q);
    q = vfma2(rot16<14>(h2), u2r[14], q);
    q = vfma2(rot16<15>(h2), u2r[15], q);
    h2 = gate2(whv[t] + q, h2, bgB, KB, nzgB, AB, false);
  }

  out[(size_t)n0 * 64 + lane] = h2.x;
  out[(size_t)n1 * 64 + lane] = h2.y;
}

extern "C" void kernel_launch(void* const* d_in, const int* in_sizes, int n_in,
                              void* d_out, int out_size, void* d_ws, size_t ws_size,
                              hipStream_t stream) {
  const float* inp   = (const float*)d_in[0];
  const float* W1    = (const float*)d_in[1];
  const float* U1    = (const float*)d_in[2];
  const float* bg1   = (const float*)d_in[3];
  const float* bu1   = (const float*)d_in[4];
  const float* zeta1 = (const float*)d_in[5];
  const float* nu1   = (const float*)d_in[6];
  const float* W2    = (const float*)d_in[7];
  const float* U2    = (const float*)d_in[8];
  const float* bg2   = (const float*)d_in[9];
  const float* bu2   = (const float*)d_in[10];
  const float* zeta2 = (const float*)d_in[11];
  const float* nu2   = (const float*)d_in[12];
  float* out = (float*)d_out;

  const size_t HSZ = (size_t)32 * 27 * 112 * 8;  // floats per h buffer
  float* hrowg = (float*)d_ws;
  float* hcolg = hrowg + HSZ;

  // K1: 12096 pair-waves (row+col), 4/block
  l1_kernel<<<dim3(3024), dim3(256), 0, stream>>>(
      inp, W1, U1, bg1, bu1, zeta1, nu1, hrowg, hcolg);
  // K2: 11664 patch-pair waves, 4/block
  l2_kernel<<<dim3(2916), dim3(256), 0, stream>>>(
      hrowg, hcolg, W2, U2, bg2, bu2, zeta2, nu2, out);
}